// Round 1
// baseline (7440.903 us; speedup 1.0000x reference)
//
#include <hip/hip_runtime.h>
#include <hip/hip_bf16.h>

#define HID   512
#define BATCH 128
#define TLEN  1024
#define OUTD  10
#define NWAVE 8
#define WGSZ  (NWAVE * 64)
#define NWG   (BATCH / 16)   // 8 workgroups, 16 chains each

typedef __attribute__((ext_vector_type(8))) short bf16x8;   // 8 bf16 = 4 VGPRs
typedef __attribute__((ext_vector_type(4))) float f32x4;    // MFMA C/D frag

#if __has_builtin(__builtin_amdgcn_exp2f)
#define EXP2F __builtin_amdgcn_exp2f
#else
#define EXP2F exp2f
#endif
#if __has_builtin(__builtin_amdgcn_rcpf)
#define RCPF __builtin_amdgcn_rcpf
#else
#define RCPF(x) (1.0f / (x))
#endif

static __device__ __forceinline__ ushort f2bf(float f) {
    __hip_bfloat16 h = __float2bfloat16(f);   // RNE
    return *reinterpret_cast<ushort*>(&h);
}

// Pack W2 (fp32 [512][512], z = h @ W2^T) into bf16 MFMA B-fragment-major layout.
// frag id = wv*64 + kt*4 + nt ; lane l holds W2[j = wv*64+nt*16+(l&15)][k = kt*32+(l>>4)*8 + i]
__global__ __launch_bounds__(256) void pack_w2_kernel(const float* __restrict__ W2,
                                                      ushort* __restrict__ w2f) {
    int tid  = blockIdx.x * 256 + threadIdx.x;  // 0..32767
    int l    = tid & 63;
    int frag = tid >> 6;                        // 0..511
    int wv   = frag >> 6;
    int kt   = (frag >> 2) & 15;
    int nt   = frag & 3;
    int j = wv * 64 + nt * 16 + (l & 15);
    int k = kt * 32 + (l >> 4) * 8;
    const float* src = W2 + j * HID + k;
    bf16x8 v;
#pragma unroll
    for (int i = 0; i < 8; ++i) v[i] = (short)f2bf(src[i]);
    *reinterpret_cast<bf16x8*>(w2f + frag * 512 + l * 8) = v;
}

// Transpose x [128][1024] -> xT [1024][128] so each step reads 16 contiguous floats.
__global__ __launch_bounds__(512) void pack_x_kernel(const float* __restrict__ x,
                                                     float* __restrict__ xT) {
    int tid = blockIdx.x * 512 + threadIdx.x;   // 0..131071
    int b = tid >> 10;
    int t = tid & 1023;
    xT[t * BATCH + b] = x[b * TLEN + t];
}

__global__ __launch_bounds__(WGSZ) void rnn_kernel(const ushort* __restrict__ w2f,
                                                   const float* __restrict__ xT,
                                                   const float* __restrict__ W1,
                                                   const float* __restrict__ W3,
                                                   const float* __restrict__ bh,
                                                   float* __restrict__ out) {
    // h state, bf16, double-buffered, XOR-swizzled (row pitch 1024B is 16-way conflict otherwise)
    __shared__ ushort hbuf[2][16 * 512];        // 32 KB
    __shared__ float  ybuf[2][NWAVE * 256];     // 16 KB  (per-wave y partials)

    const int tid  = threadIdx.x;
    const int l    = tid & 63;
    const int wv   = tid >> 6;        // wave 0..7, owns j-slice [wv*64, wv*64+64)
    const int lrow = l & 15;
    const int lgrp = l >> 4;          // 0..3
    const int b0   = blockIdx.x * 16;
    const int hswz = (lrow & 7) << 3; // swizzle term for reads where row = lrow
    const int wbase = wv * 64;

    // h0 = 0
    for (int i = tid; i < 16 * 512; i += WGSZ) hbuf[0][i] = 0;

    // Per-nt epilogue constants: W1[j], b_h[j] at j = wbase + nt*16 + lrow
    float w1v[4], bhv[4];
#pragma unroll
    for (int nt = 0; nt < 4; ++nt) {
        int j = wbase + nt * 16 + lrow;
        w1v[nt] = W1[j];
        bhv[nt] = bh[j];
    }
    // W3 B-fragments for the y-GEMM; this wave covers k in [wbase, wbase+64)
    bf16x8 w3f[2];
#pragma unroll
    for (int kk = 0; kk < 2; ++kk) {
#pragma unroll
        for (int i = 0; i < 8; ++i) {
            int k = wbase + kk * 32 + lgrp * 8 + i;
            float v = (lrow < OUTD) ? W3[lrow * HID + k] : 0.0f;
            w3f[kk][i] = (short)f2bf(v);
        }
    }

    const bf16x8* w2ff = reinterpret_cast<const bf16x8*>(w2f);

    // 2-deep kt software pipeline of W2 B-fragments (register-resident, L2-hit after step 0)
    bf16x8 bq[2][4];
#pragma unroll
    for (int p = 0; p < 2; ++p)
#pragma unroll
        for (int nt = 0; nt < 4; ++nt)
            bq[p][nt] = w2ff[(wbase + p * 4 + nt) * 64 + l];

    // x for step 0 (and step-ahead prefetch inside the loop)
    float x4[4], xn[4];
#pragma unroll
    for (int q = 0; q < 4; ++q) x4[q] = xT[b0 + lgrp * 4 + q];

    __syncthreads();

    for (int t = 0; t < TLEN; ++t) {
        const int cur = t & 1, nxt = cur ^ 1;
        const ushort* hc = hbuf[cur];
        ushort* hn = hbuf[nxt];

        // prefetch next step's x early (hides cold-HBM latency off the critical path)
        {
            int tn = (t + 1 < TLEN) ? t + 1 : t;
#pragma unroll
            for (int q = 0; q < 4; ++q) xn[q] = xT[tn * BATCH + b0 + lgrp * 4 + q];
        }

        f32x4 acc[4] = {{0.f,0.f,0.f,0.f},{0.f,0.f,0.f,0.f},{0.f,0.f,0.f,0.f},{0.f,0.f,0.f,0.f}};

#pragma unroll
        for (int kt = 0; kt < 16; ++kt) {
            const int slot = kt & 1;
            // A-frag: h[lrow][kt*32 + lgrp*8 + 0..7], swizzled ds_read_b128
            bf16x8 af = *reinterpret_cast<const bf16x8*>(
                &hc[(lrow * 512 + kt * 32 + lgrp * 8) ^ hswz]);
            acc[0] = __builtin_amdgcn_mfma_f32_16x16x32_bf16(af, bq[slot][0], acc[0], 0, 0, 0);
            acc[1] = __builtin_amdgcn_mfma_f32_16x16x32_bf16(af, bq[slot][1], acc[1], 0, 0, 0);
            acc[2] = __builtin_amdgcn_mfma_f32_16x16x32_bf16(af, bq[slot][2], acc[2], 0, 0, 0);
            acc[3] = __builtin_amdgcn_mfma_f32_16x16x32_bf16(af, bq[slot][3], acc[3], 0, 0, 0);
            // refill this slot for kt+2 (wraps into next step's kt 0/1: same addresses, W2 constant)
            const int kt2 = (kt + 2) & 15;
#pragma unroll
            for (int nt = 0; nt < 4; ++nt)
                bq[slot][nt] = w2ff[(wbase + kt2 * 4 + nt) * 64 + l];
        }

        // epilogue: z = acc + x*W1 + b_h ; h = tanh(z) ; store bf16 to next h buffer
#pragma unroll
        for (int nt = 0; nt < 4; ++nt) {
#pragma unroll
            for (int q = 0; q < 4; ++q) {
                float z  = acc[nt][q] + x4[q] * w1v[nt] + bhv[nt];
                float e2 = EXP2F(z * 2.885390082f);            // e^(2z) = 2^(2z*log2e)
                float th = 1.0f - 2.0f * RCPF(e2 + 1.0f);      // tanh(z)
                int row = lgrp * 4 + q;                        // chain index (C-frag row)
                int col = wbase + nt * 16 + lrow;              // hidden index (C-frag col)
                hn[(row * 512 + col) ^ ((row & 7) << 3)] = f2bf(th);
            }
        }
        asm volatile("s_waitcnt lgkmcnt(0)" ::: "memory");  // own h writes visible to own reads

        // y partial: this wave's k-slice of y_t = h_new @ W3^T (2 MFMAs, K=64)
        f32x4 yacc = {0.f, 0.f, 0.f, 0.f};
#pragma unroll
        for (int kk = 0; kk < 2; ++kk) {
            bf16x8 af = *reinterpret_cast<const bf16x8*>(
                &hn[(lrow * 512 + wbase + kk * 32 + lgrp * 8) ^ hswz]);
            yacc = __builtin_amdgcn_mfma_f32_16x16x32_bf16(af, w3f[kk], yacc, 0, 0, 0);
        }
        *reinterpret_cast<f32x4*>(&ybuf[cur][wv * 256 + l * 4]) = yacc;

#pragma unroll
        for (int q = 0; q < 4; ++q) x4[q] = xn[q];

        __syncthreads();   // one barrier per step: h_new + y partials published

        // wave 0 reduces y partials and stores; overlaps other waves' next-step MFMAs.
        // ybuf[cur] is not rewritten until step t+2's epilogue (after t+1's barrier) -> safe.
        if (wv == 0) {
            const f32x4* yb = reinterpret_cast<const f32x4*>(&ybuf[cur][0]);
            f32x4 s = yb[l];
#pragma unroll
            for (int wi = 1; wi < 8; ++wi) s += yb[wi * 64 + l];
            if (lrow < OUTD) {
#pragma unroll
                for (int q = 0; q < 4; ++q)
                    out[((b0 + lgrp * 4 + q) * TLEN + t) * OUTD + lrow] = s[q];
            }
        }
    }
}

extern "C" void kernel_launch(void* const* d_in, const int* in_sizes, int n_in,
                              void* d_out, int out_size, void* d_ws, size_t ws_size,
                              hipStream_t stream) {
    const float* x  = (const float*)d_in[0];   // [128][1024]
    const float* W1 = (const float*)d_in[1];   // [512]
    const float* W2 = (const float*)d_in[2];   // [512][512]
    const float* W3 = (const float*)d_in[3];   // [10][512]
    const float* bh = (const float*)d_in[4];   // [512]
    float* out = (float*)d_out;                // [128][1024][10]

    ushort* w2f = (ushort*)d_ws;                         // 512 KB fragment-packed W2
    float*  xT  = (float*)((char*)d_ws + (512 << 10));   // 512 KB transposed x

    hipLaunchKernelGGL(pack_w2_kernel, dim3(128), dim3(256), 0, stream, W2, w2f);
    hipLaunchKernelGGL(pack_x_kernel,  dim3(256), dim3(512), 0, stream, x, xT);
    hipLaunchKernelGGL(rnn_kernel, dim3(NWG), dim3(WGSZ), 0, stream,
                       w2f, xT, W1, W3, bh, out);
}

// Round 2
// 2759.018 us; speedup vs baseline: 2.6969x; 2.6969x over previous
//
#include <hip/hip_runtime.h>
#include <hip/hip_bf16.h>

#define HID   512
#define BATCH 128
#define TLEN  1024
#define OUTD  10
#define NWAVE 8
#define WGSZ  (NWAVE * 64)
#define NWG   (BATCH / 16)   // 8 workgroups, 16 chains each
#define KT_REG 12            // kt 0..11 W2 fragments in VGPRs (192 regs/wave)
#define KT_LDS 4             // kt 12..15 W2 fragments in LDS (16 KB/wave)

typedef __attribute__((ext_vector_type(8))) short bf16x8;   // 8 bf16 = 4 VGPRs
typedef __attribute__((ext_vector_type(4))) float f32x4;    // MFMA C/D frag

#if __has_builtin(__builtin_amdgcn_exp2f)
#define EXP2F __builtin_amdgcn_exp2f
#else
#define EXP2F exp2f
#endif
#if __has_builtin(__builtin_amdgcn_rcpf)
#define RCPF __builtin_amdgcn_rcpf
#else
#define RCPF(x) (1.0f / (x))
#endif

static __device__ __forceinline__ ushort f2bf(float f) {
    __hip_bfloat16 h = __float2bfloat16(f);   // RNE
    return *reinterpret_cast<ushort*>(&h);
}

// Pack W2 (fp32 [512][512], z = h @ W2^T) into bf16 MFMA B-fragment-major layout.
// frag id = wv*64 + kt*4 + nt ; lane l holds W2[j = wv*64+nt*16+(l&15)][k = kt*32+(l>>4)*8 + i]
__global__ __launch_bounds__(256) void pack_w2_kernel(const float* __restrict__ W2,
                                                      ushort* __restrict__ w2f) {
    int tid  = blockIdx.x * 256 + threadIdx.x;  // 0..32767
    int l    = tid & 63;
    int frag = tid >> 6;                        // 0..511
    int wv   = frag >> 6;
    int kt   = (frag >> 2) & 15;
    int nt   = frag & 3;
    int j = wv * 64 + nt * 16 + (l & 15);
    int k = kt * 32 + (l >> 4) * 8;
    const float* src = W2 + j * HID + k;
    bf16x8 v;
#pragma unroll
    for (int i = 0; i < 8; ++i) v[i] = (short)f2bf(src[i]);
    *reinterpret_cast<bf16x8*>(w2f + frag * 512 + l * 8) = v;
}

// Transpose x [128][1024] -> xT [1024][128] so each step reads 16 contiguous floats.
__global__ __launch_bounds__(512) void pack_x_kernel(const float* __restrict__ x,
                                                     float* __restrict__ xT) {
    int tid = blockIdx.x * 512 + threadIdx.x;   // 0..131071
    int b = tid >> 10;
    int t = tid & 1023;
    xT[t * BATCH + b] = x[b * TLEN + t];
}

__global__ __launch_bounds__(WGSZ, 2) void rnn_kernel(const ushort* __restrict__ w2f,
                                                      const float* __restrict__ xT,
                                                      const float* __restrict__ W1,
                                                      const float* __restrict__ W3,
                                                      const float* __restrict__ bh,
                                                      float* __restrict__ out) {
    // W2 tail (kt 12..15): [wave][frag 0..15][lane*8+i], 16 KB/wave = 128 KB
    __shared__ ushort w2lds[NWAVE * KT_LDS * 4 * 512];
    // h state, bf16, SINGLE buffer, XOR-swizzled; overwritten in epilogue behind barrier
    __shared__ ushort hbuf[16 * 512];           // 16 KB
    __shared__ float  ybuf[NWAVE * 256];        // 8 KB  (per-wave y partials)

    const int tid  = threadIdx.x;
    const int l    = tid & 63;
    const int wv   = tid >> 6;        // wave 0..7, owns j-slice [wv*64, wv*64+64)
    const int lrow = l & 15;
    const int lgrp = l >> 4;          // 0..3
    const int b0   = blockIdx.x * 16;
    const int hswz = (lrow & 7) << 3; // swizzle term for reads where row = lrow
    const int wbase = wv * 64;

    // h0 = 0
    for (int i = tid; i < 16 * 512; i += WGSZ) hbuf[i] = 0;

    const bf16x8* w2ff = reinterpret_cast<const bf16x8*>(w2f);

    // --- W2 residency ---
    // kt 0..11 in registers: 48 frags x 4 VGPRs = 192 VGPRs (all indices static)
    bf16x8 breg[KT_REG][4];
#pragma unroll
    for (int kt = 0; kt < KT_REG; ++kt)
#pragma unroll
        for (int nt = 0; nt < 4; ++nt)
            breg[kt][nt] = w2ff[(wbase + kt * 4 + nt) * 64 + l];
    // kt 12..15 into LDS (one-time copy)
#pragma unroll
    for (int f = 0; f < KT_LDS * 4; ++f) {
        bf16x8 v = w2ff[(wbase + KT_REG * 4 + f) * 64 + l];
        *reinterpret_cast<bf16x8*>(&w2lds[(wv * 16 + f) * 512 + l * 8]) = v;
    }

    // Per-nt epilogue constants: W1[j], b_h[j] at j = wbase + nt*16 + lrow
    float w1v[4], bhv[4];
#pragma unroll
    for (int nt = 0; nt < 4; ++nt) {
        int j = wbase + nt * 16 + lrow;
        w1v[nt] = W1[j];
        bhv[nt] = bh[j];
    }
    // W3 B-fragments for the y-GEMM; this wave covers k in [wbase, wbase+64)
    bf16x8 w3f[2];
#pragma unroll
    for (int kk = 0; kk < 2; ++kk) {
#pragma unroll
        for (int i = 0; i < 8; ++i) {
            int k = wbase + kk * 32 + lgrp * 8 + i;
            float v = (lrow < OUTD) ? W3[lrow * HID + k] : 0.0f;
            w3f[kk][i] = (short)f2bf(v);
        }
    }

    // x for step 0 (and step-ahead prefetch inside the loop)
    float x4[4], xn[4];
#pragma unroll
    for (int q = 0; q < 4; ++q) x4[q] = xT[b0 + lgrp * 4 + q];

    __syncthreads();

    for (int t = 0; t < TLEN; ++t) {
        // prefetch next step's x early (off the critical path)
        {
            int tn = (t + 1 < TLEN) ? t + 1 : t;
#pragma unroll
            for (int q = 0; q < 4; ++q) xn[q] = xT[tn * BATCH + b0 + lgrp * 4 + q];
        }

        f32x4 acc[4] = {{0.f,0.f,0.f,0.f},{0.f,0.f,0.f,0.f},{0.f,0.f,0.f,0.f},{0.f,0.f,0.f,0.f}};

        // kt 0..11: B from registers (zero memory traffic beyond the A-frag read)
#pragma unroll
        for (int kt = 0; kt < KT_REG; ++kt) {
            bf16x8 af = *reinterpret_cast<const bf16x8*>(
                &hbuf[(lrow * 512 + kt * 32 + lgrp * 8) ^ hswz]);
            acc[0] = __builtin_amdgcn_mfma_f32_16x16x32_bf16(af, breg[kt][0], acc[0], 0, 0, 0);
            acc[1] = __builtin_amdgcn_mfma_f32_16x16x32_bf16(af, breg[kt][1], acc[1], 0, 0, 0);
            acc[2] = __builtin_amdgcn_mfma_f32_16x16x32_bf16(af, breg[kt][2], acc[2], 0, 0, 0);
            acc[3] = __builtin_amdgcn_mfma_f32_16x16x32_bf16(af, breg[kt][3], acc[3], 0, 0, 0);
        }
        // kt 12..15: B from LDS (conflict-free stride-1 b128 reads)
#pragma unroll
        for (int kt = KT_REG; kt < 16; ++kt) {
            bf16x8 af = *reinterpret_cast<const bf16x8*>(
                &hbuf[(lrow * 512 + kt * 32 + lgrp * 8) ^ hswz]);
#pragma unroll
            for (int nt = 0; nt < 4; ++nt) {
                bf16x8 bf = *reinterpret_cast<const bf16x8*>(
                    &w2lds[(wv * 16 + (kt - KT_REG) * 4 + nt) * 512 + l * 8]);
                acc[nt] = __builtin_amdgcn_mfma_f32_16x16x32_bf16(af, bf, acc[nt], 0, 0, 0);
            }
        }

        __syncthreads();   // B1: all A-reads of h_t complete -> safe to overwrite hbuf

        // epilogue: z = acc + x*W1 + b_h ; h = tanh(z) ; write h_{t+1} over hbuf
#pragma unroll
        for (int nt = 0; nt < 4; ++nt) {
#pragma unroll
            for (int q = 0; q < 4; ++q) {
                float z  = acc[nt][q] + x4[q] * w1v[nt] + bhv[nt];
                float e2 = EXP2F(z * 2.885390082f);            // e^(2z) = 2^(2z*log2e)
                float th = 1.0f - 2.0f * RCPF(e2 + 1.0f);      // tanh(z)
                int row = lgrp * 4 + q;                        // chain index (C-frag row)
                int col = wbase + nt * 16 + lrow;              // hidden index (C-frag col)
                hbuf[(row * 512 + col) ^ ((row & 7) << 3)] = f2bf(th);
            }
        }
        asm volatile("s_waitcnt lgkmcnt(0)" ::: "memory");  // own h writes visible to own reads

        // y partial: this wave's k-slice of y_t = h_new @ W3^T (reads only own-written cols)
        f32x4 yacc = {0.f, 0.f, 0.f, 0.f};
#pragma unroll
        for (int kk = 0; kk < 2; ++kk) {
            bf16x8 af = *reinterpret_cast<const bf16x8*>(
                &hbuf[(lrow * 512 + wbase + kk * 32 + lgrp * 8) ^ hswz]);
            yacc = __builtin_amdgcn_mfma_f32_16x16x32_bf16(af, w3f[kk], yacc, 0, 0, 0);
        }
        *reinterpret_cast<f32x4*>(&ybuf[wv * 256 + l * 4]) = yacc;

#pragma unroll
        for (int q = 0; q < 4; ++q) x4[q] = xn[q];

        __syncthreads();   // B2: h_{t+1} + y partials published

        // wave 0 reduces y partials and stores; overlaps other waves' next-step MFMAs.
        // ybuf not rewritten until next epilogue (behind next B1, which wave0 also gates).
        if (wv == 0) {
            const f32x4* yb = reinterpret_cast<const f32x4*>(&ybuf[0]);
            f32x4 s = yb[l];
#pragma unroll
            for (int wi = 1; wi < 8; ++wi) s += yb[wi * 64 + l];
            if (lrow < OUTD) {
#pragma unroll
                for (int q = 0; q < 4; ++q)
                    out[((b0 + lgrp * 4 + q) * TLEN + t) * OUTD + lrow] = s[q];
            }
        }
    }
}

extern "C" void kernel_launch(void* const* d_in, const int* in_sizes, int n_in,
                              void* d_out, int out_size, void* d_ws, size_t ws_size,
                              hipStream_t stream) {
    const float* x  = (const float*)d_in[0];   // [128][1024]
    const float* W1 = (const float*)d_in[1];   // [512]
    const float* W2 = (const float*)d_in[2];   // [512][512]
    const float* W3 = (const float*)d_in[3];   // [10][512]
    const float* bh = (const float*)d_in[4];   // [512]
    float* out = (float*)d_out;                // [128][1024][10]

    ushort* w2f = (ushort*)d_ws;                         // 512 KB fragment-packed W2
    float*  xT  = (float*)((char*)d_ws + (512 << 10));   // 512 KB transposed x

    hipLaunchKernelGGL(pack_w2_kernel, dim3(128), dim3(256), 0, stream, W2, w2f);
    hipLaunchKernelGGL(pack_x_kernel,  dim3(256), dim3(512), 0, stream, x, xT);
    hipLaunchKernelGGL(rnn_kernel, dim3(NWG), dim3(WGSZ), 0, stream,
                       w2f, xT, W1, W3, bh, out);
}